// Round 5
// baseline (131.703 us; speedup 1.0000x reference)
//
#include <hip/hip_runtime.h>

// Problem constants (fixed by setup_inputs)
constexpr int B_ = 8, C_ = 64, O_ = 64, H_ = 128, W_ = 128;
constexpr int K2_ = 9, OFFC = 18;          // 2*K2
constexpr int NPIX = B_ * H_ * W_;         // 131072

typedef __attribute__((ext_vector_type(8))) short bf16x8;
typedef __attribute__((ext_vector_type(4))) short bf16x4;
typedef __attribute__((ext_vector_type(4))) float f32x4;

__device__ __forceinline__ unsigned short f2bf(float f) {
    unsigned int u = __float_as_uint(f);
    u += 0x7fffu + ((u >> 16) & 1u);       // round-to-nearest-even
    return (unsigned short)(u >> 16);
}
__device__ __forceinline__ float bf2f(unsigned short s) {
    return __uint_as_float(((unsigned)s) << 16);
}
__device__ __forceinline__ float tobf_f(float v) {   // round-trip through bf16
    return bf2f(f2bf(v));
}

// ---------------------------------------------------------------------------
// K0b: w_def (O,C,3,3) -> wTfrag, bf16 in MFMA B-fragment order.
// frag f = kc*4 + nt; lane l, elem j: oc = nt*16+(l&15); K = kc*32+(l>>4)*8+j
// K = tap*64 + c
// ---------------------------------------------------------------------------
__global__ void k_wprep(const float* __restrict__ w_def,
                        unsigned short* __restrict__ wTfrag) {
    int i = blockIdx.x * 256 + threadIdx.x;           // over 72*512 = 36864
    if (i >= O_ * C_ * K2_) return;
    int f = i >> 9;            // /512
    int l = (i >> 3) & 63;
    int j = i & 7;
    int kc = f >> 2, nt = f & 3;
    int oc = nt * 16 + (l & 15);
    int K  = kc * 32 + ((l >> 4) << 3) + j;
    int tap = K >> 6, c = K & 63;
    wTfrag[i] = f2bf(w_def[(size_t)oc * (C_ * K2_) + c * K2_ + tap]);
}

// ---------------------------------------------------------------------------
// K0c: w_off (18,C,3,3) -> wOfrag, bf16 B-fragment order, N padded 18->32.
// ---------------------------------------------------------------------------
__global__ void k_wprep_off(const float* __restrict__ w_off,
                            unsigned short* __restrict__ wOfrag) {
    int i = blockIdx.x * 256 + threadIdx.x;           // over 36*512 = 18432
    if (i >= 36 * 512) return;
    int f = i >> 9;
    int l = (i >> 3) & 63;
    int j = i & 7;
    int kc = f >> 1, nt = f & 1;
    int oc = nt * 16 + (l & 15);
    int K  = kc * 32 + ((l >> 4) << 3) + j;
    int tap = K >> 6, c = K & 63;
    float v = (oc < OFFC) ? w_off[((size_t)oc * C_ + c) * K2_ + tap] : 0.f;
    wOfrag[i] = f2bf(v);
}

// ---------------------------------------------------------------------------
// K1: fully fused with LDS x-stage.
// Block = 64 px (one row segment), 256 threads (4 waves).
// xs: x window rows h-2..h+2, cols w0-3..w0+68, bf16.
//     Layout [q=ch/16][entry=(r,col)][16ch], entry = 32 B.
//     Swizzle: byte ^= ((col&7)<<4) ^ (q<<5).
//     BIJECTIVITY: QS = 360*32 and 360 % 8 == 0, 72 % 8 == 0 ==>
//     global entry index E = q*360 + r*72 + col satisfies E&7 == col&7,
//     and partitions are whole 8-entry blocks, so addresses differing only
//     in bits 4-6 share q; then E2=b7, E1=b6^E2^q1, E0=b5^E1^q0, o4=b4^E0
//     inverts uniquely. (The round-4 bug: +32 B pad made the base 361
//     entries, 361%8==1, breaking E&7==col&7 -> write collisions.)
// tile: [64 px][192 K] bf16 per 3-tap chunk, addr ^= (px&7)<<4 (row stride
//     384 B, post-XOR offset < 384 -> bijective; proven in round 3).
// ---------------------------------------------------------------------------
constexpr int QS = 5 * 72 * 32;            // 11520 B per q partition (360 entries)
constexpr int XS_BYTES = 4 * QS;           // 46080
constexpr int TILE_BYTES = 64 * 384;       // 24576

__global__ __launch_bounds__(256, 2) void k_fused(const float* __restrict__ x,
                                                  const unsigned short* __restrict__ wOfrag,
                                                  const float* __restrict__ b_off,
                                                  const unsigned short* __restrict__ wTfrag,
                                                  const float* __restrict__ b_def,
                                                  float* __restrict__ out) {
    __shared__ __align__(16) char xs[XS_BYTES];
    __shared__ __align__(16) char tile[TILE_BYTES];
    __shared__ float offsBuf[64][20];

    int bid = blockIdx.x;                  // grid = 2048; chunked XCD swizzle
    int swz = (bid & 7) * 256 + (bid >> 3);
    int px0 = swz * 64;
    int b  = px0 >> 14;
    int h  = (px0 >> 7) & (H_ - 1);
    int w0 = px0 & (W_ - 1);               // 0 or 64

    int tid  = threadIdx.x;
    int lane = tid & 63;
    int wave = tid >> 6;

    // --- main-GEMM B-fragment preload (hidden under staging) ---
    bf16x8 Bf[18];
    #pragma unroll
    for (int kc = 0; kc < 18; ++kc) {
        Bf[kc] = *reinterpret_cast<const bf16x8*>(
            wTfrag + (((kc * 4 + wave) * 64 + lane) << 3));
    }

    // --- phase 0: stage x window -> xs (bf16, zero-padded OOB) ---
    // 5760 items over (r in 5, c4 in 16, col in 72); thread handles 4 channels
    for (int it = tid; it < 5760; it += 256) {
        int col = it % 72;
        int rem = it / 72;
        int c4  = rem & 15;                // channel group of 4 (c = c4*4..+3)
        int r   = rem >> 4;                // 0..4
        int y    = h - 2 + r;
        int xcol = w0 - 3 + col;
        bf16x4 pk;
        if (((unsigned)y < (unsigned)H_) && ((unsigned)xcol < (unsigned)W_)) {
            const float* g = x + (((size_t)(b * C_ + c4 * 4) * H_ + y) * W_ + xcol);
            pk[0] = (short)f2bf(g[0]);
            pk[1] = (short)f2bf(g[H_ * W_]);
            pk[2] = (short)f2bf(g[2 * H_ * W_]);
            pk[3] = (short)f2bf(g[3 * H_ * W_]);
        } else {
            pk = (bf16x4){0, 0, 0, 0};
        }
        int q0 = c4 >> 2;
        int byte = q0 * QS + ((r * 72 + col) * 32) + (c4 & 3) * 8;
        byte ^= ((col & 7) << 4) ^ (q0 << 5);
        *reinterpret_cast<bf16x4*>(xs + byte) = pk;
    }
    __syncthreads();

    // --- phase 1: offset GEMM (A-frags straight from xs) ---
    {
        f32x4 acc2[2];
        acc2[0] = (f32x4){0.f, 0.f, 0.f, 0.f};
        acc2[1] = (f32x4){0.f, 0.f, 0.f, 0.f};
        int g   = lane >> 4;
        int pxr = wave * 16 + (lane & 15);
        #pragma unroll
        for (int kc = 0; kc < 18; ++kc) {
            int K   = kc * 32 + g * 8;
            int tap = K >> 6, c = K & 63;
            int ky = tap / 3, kx = tap % 3;
            int col = pxr + kx + 2;        // x=(w0+pxr)-1+kx ; col = x-(w0-3)
            int r   = ky + 1;              // y=h-1+ky ; r = y-(h-2)
            int qq  = c >> 4;
            int byte = qq * QS + ((r * 72 + col) * 32) + (c & 15) * 2;
            byte ^= ((col & 7) << 4) ^ (qq << 5);
            bf16x8 a  = *reinterpret_cast<const bf16x8*>(xs + byte);
            bf16x8 b0 = *reinterpret_cast<const bf16x8*>(wOfrag + (((kc * 2 + 0) * 64 + lane) << 3));
            bf16x8 b1 = *reinterpret_cast<const bf16x8*>(wOfrag + (((kc * 2 + 1) * 64 + lane) << 3));
            acc2[0] = __builtin_amdgcn_mfma_f32_16x16x32_bf16(a, b0, acc2[0], 0, 0, 0);
            acc2[1] = __builtin_amdgcn_mfma_f32_16x16x32_bf16(a, b1, acc2[1], 0, 0, 0);
        }
        #pragma unroll
        for (int nt = 0; nt < 2; ++nt) {
            int oc = nt * 16 + (lane & 15);
            if (oc < OFFC) {
                float bo = b_off[oc];
                #pragma unroll
                for (int j = 0; j < 4; ++j) {
                    int px = wave * 16 + ((lane >> 4) << 2) + j;
                    offsBuf[px][oc] = acc2[nt][j] + bo;
                }
            }
        }
    }
    __syncthreads();

    // --- phases 2..4: 3 chunks of {sample 3 taps -> tile ; GEMM} ---
    f32x4 acc[4];
    #pragma unroll
    for (int m = 0; m < 4; ++m) acc[m] = (f32x4){0.f, 0.f, 0.f, 0.f};

    int spx = tid >> 2;                    // sampling pixel
    int q   = tid & 3;                     // 16-ch quarter
    int wg  = w0 + spx;
    char* trow = tile + spx * 384;
    unsigned rs = (unsigned)((spx & 7) << 4);
    int colbase = (lane >> 4) << 4;        // GEMM A byte col base
    int qs5 = q << 5;                      // xs q-swizzle bits

    for (int chunk = 0; chunk < 3; ++chunk) {
        // sampling: taps 3*chunk .. +2
        #pragma unroll
        for (int kk = 0; kk < 3; ++kk) {
            int k  = chunk * 3 + kk;
            int ky = chunk, kx = kk;       // k = 3*chunk + kk
            float2 dv = *reinterpret_cast<const float2*>(&offsBuf[spx][2 * k]);
            float py  = (float)(h - 1 + ky) + dv.x;
            float pxf = (float)(wg - 1 + kx) + dv.y;
            float y0f = floorf(py), x0f = floorf(pxf);
            float wy = py - y0f, wx = pxf - x0f;
            int y0 = (int)y0f, x0 = (int)x0f;
            int r0 = y0 - (h - 2);
            int c0 = x0 - (w0 - 3);
            float w00 = (1.f - wy) * (1.f - wx);
            float w01 = (1.f - wy) * wx;
            float w10 = wy * (1.f - wx);
            float w11 = wy * wx;

            float s[16];
            if (((unsigned)r0 < 4u) && ((unsigned)c0 < 71u)) {
                // fast path: all 4 corners inside the staged window
                int base = q * QS;
                int A00 = base + ((r0 * 72 + c0) * 32);
                int A01 = base + ((r0 * 72 + c0 + 1) * 32);
                int A10 = A00 + 72 * 32;
                int A11 = A01 + 72 * 32;
                int s0 = ((c0 & 7) << 4) ^ qs5;
                int s1 = (((c0 + 1) & 7) << 4) ^ qs5;
                int L00 = A00 ^ s0;
                int L01 = A01 ^ s1;
                int L10 = A10 ^ s0;
                int L11 = A11 ^ s1;
                bf16x8 p00a = *reinterpret_cast<const bf16x8*>(xs + L00);
                bf16x8 p00b = *reinterpret_cast<const bf16x8*>(xs + (L00 ^ 16));
                bf16x8 p01a = *reinterpret_cast<const bf16x8*>(xs + L01);
                bf16x8 p01b = *reinterpret_cast<const bf16x8*>(xs + (L01 ^ 16));
                bf16x8 p10a = *reinterpret_cast<const bf16x8*>(xs + L10);
                bf16x8 p10b = *reinterpret_cast<const bf16x8*>(xs + (L10 ^ 16));
                bf16x8 p11a = *reinterpret_cast<const bf16x8*>(xs + L11);
                bf16x8 p11b = *reinterpret_cast<const bf16x8*>(xs + (L11 ^ 16));
                #pragma unroll
                for (int chi = 0; chi < 8; ++chi) {
                    s[chi] = w00 * bf2f((unsigned short)p00a[chi])
                           + w01 * bf2f((unsigned short)p01a[chi])
                           + w10 * bf2f((unsigned short)p10a[chi])
                           + w11 * bf2f((unsigned short)p11a[chi]);
                    s[8 + chi] = w00 * bf2f((unsigned short)p00b[chi])
                               + w01 * bf2f((unsigned short)p01b[chi])
                               + w10 * bf2f((unsigned short)p10b[chi])
                               + w11 * bf2f((unsigned short)p11b[chi]);
                }
            } else {
                // slow path (rare): reference semantics from global NCHW
                int y1 = y0 + 1, x1 = x0 + 1;
                bool vy0 = (y0 >= 0) & (y0 < H_);
                bool vy1 = (y1 >= 0) & (y1 < H_);
                bool vx0 = (x0 >= 0) & (x0 < W_);
                bool vx1 = (x1 >= 0) & (x1 < W_);
                float m00 = (vy0 && vx0) ? w00 : 0.f;
                float m01 = (vy0 && vx1) ? w01 : 0.f;
                float m10 = (vy1 && vx0) ? w10 : 0.f;
                float m11 = (vy1 && vx1) ? w11 : 0.f;
                int y0c = min(max(y0, 0), H_ - 1), y1c = min(max(y1, 0), H_ - 1);
                int x0c = min(max(x0, 0), W_ - 1), x1c = min(max(x1, 0), W_ - 1);
                const float* cb = x + ((size_t)(b * C_ + q * 16) * H_) * W_;
                #pragma unroll
                for (int chi = 0; chi < 16; ++chi) {
                    const float* cc = cb + (size_t)chi * H_ * W_;
                    float v00 = tobf_f(cc[y0c * W_ + x0c]);
                    float v01 = tobf_f(cc[y0c * W_ + x1c]);
                    float v10 = tobf_f(cc[y1c * W_ + x0c]);
                    float v11 = tobf_f(cc[y1c * W_ + x1c]);
                    s[chi] = m00 * v00 + m01 * v01 + m10 * v10 + m11 * v11;
                }
            }
            bf16x8 v0, v1;
            #pragma unroll
            for (int j = 0; j < 8; ++j) {
                v0[j] = (short)f2bf(s[j]);
                v1[j] = (short)f2bf(s[8 + j]);
            }
            unsigned ib = (unsigned)(kk * 128 + q * 32);   // K' = kk*64 + q*16
            *reinterpret_cast<bf16x8*>(trow + (ib ^ rs)) = v0;
            *reinterpret_cast<bf16x8*>(trow + ((ib ^ rs) ^ 16)) = v1;
        }
        __syncthreads();

        // GEMM over this chunk (K' = 192, kl local 0..5)
        #pragma unroll
        for (int m = 0; m < 4; ++m) {
            int row = m * 16 + (lane & 15);
            const char* rbase = tile + row * 384;
            unsigned rsw = (unsigned)((row & 7) << 4);
            #pragma unroll
            for (int kl = 0; kl < 6; ++kl) {
                bf16x8 a = *reinterpret_cast<const bf16x8*>(
                    rbase + (((unsigned)(kl * 64 + colbase)) ^ rsw));
                acc[m] = __builtin_amdgcn_mfma_f32_16x16x32_bf16(a, Bf[chunk * 6 + kl], acc[m], 0, 0, 0);
            }
        }
        __syncthreads();
    }

    // --- epilogue: stage 64px x 64oc f32 (reuse tile), coalesced NCHW store ---
    float* ot = reinterpret_cast<float*>(tile);          // [64][65]
    float bias = b_def[wave * 16 + (lane & 15)];
    #pragma unroll
    for (int m = 0; m < 4; ++m) {
        #pragma unroll
        for (int j = 0; j < 4; ++j) {
            int prow = m * 16 + ((lane >> 4) << 2) + j;   // pixel
            ot[prow * 65 + wave * 16 + (lane & 15)] = acc[m][j] + bias;
        }
    }
    __syncthreads();
    #pragma unroll
    for (int r = 0; r < 16; ++r) {
        int idx = r * 256 + tid;
        int oc = idx >> 6, pw = idx & 63;
        out[(((size_t)b * O_ + oc) * H_ + h) * W_ + w0 + pw] = ot[pw * 65 + oc];
    }
}

// ---------------------------------------------------------------------------
extern "C" void kernel_launch(void* const* d_in, const int* in_sizes, int n_in,
                              void* d_out, int out_size, void* d_ws, size_t ws_size,
                              hipStream_t stream) {
    const float* x     = (const float*)d_in[0];
    const float* w_off = (const float*)d_in[1];
    const float* b_off = (const float*)d_in[2];
    const float* w_def = (const float*)d_in[3];
    const float* b_def = (const float*)d_in[4];
    float* out = (float*)d_out;

    char* ws = (char*)d_ws;
    unsigned short* wTf = (unsigned short*)ws;            // 73,728 B
    unsigned short* wOf = (unsigned short*)(ws + 73728);  // 36,864 B

    k_wprep<<<(O_ * C_ * K2_ + 255) / 256, 256, 0, stream>>>(w_def, wTf);
    k_wprep_off<<<(36 * 512 + 255) / 256, 256, 0, stream>>>(w_off, wOf);
    k_fused<<<NPIX / 64, 256, 0, stream>>>(x, wOf, b_off, wTf, b_def, out);
}

// Round 6
// 128.746 us; speedup vs baseline: 1.0230x; 1.0230x over previous
//
#include <hip/hip_runtime.h>
#include <hip/hip_bf16.h>

// Problem constants (fixed by setup_inputs)
constexpr int B_ = 8, C_ = 64, O_ = 64, H_ = 128, W_ = 128;
constexpr int K2_ = 9, OFFC = 18;          // 2*K2
constexpr int NPIX = B_ * H_ * W_;         // 131072

typedef __attribute__((ext_vector_type(8))) short bf16x8;
typedef __attribute__((ext_vector_type(4))) short bf16x4;
typedef __attribute__((ext_vector_type(4))) float f32x4;

__device__ __forceinline__ unsigned short f2bf(float f) {
    unsigned int u = __float_as_uint(f);
    u += 0x7fffu + ((u >> 16) & 1u);       // round-to-nearest-even
    return (unsigned short)(u >> 16);
}
__device__ __forceinline__ float bf2f(unsigned short s) {
    return __uint_as_float(((unsigned)s) << 16);
}
__device__ __forceinline__ float tobf_f(float v) {   // round-trip through bf16
    return bf2f(f2bf(v));
}
__device__ __forceinline__ short f2bf_s(float f) {   // single-instr cvt path
    __hip_bfloat16 t = __float2bfloat16(f);
    return *reinterpret_cast<short*>(&t);
}

// ---------------------------------------------------------------------------
// K0b: w_def (O,C,3,3) -> wTfrag, bf16 in MFMA B-fragment order.
// frag f = kc*4 + nt; lane l, elem j: oc = nt*16+(l&15); K = kc*32+(l>>4)*8+j
// K = tap*64 + c
// ---------------------------------------------------------------------------
__global__ void k_wprep(const float* __restrict__ w_def,
                        unsigned short* __restrict__ wTfrag) {
    int i = blockIdx.x * 256 + threadIdx.x;           // over 72*512 = 36864
    if (i >= O_ * C_ * K2_) return;
    int f = i >> 9;            // /512
    int l = (i >> 3) & 63;
    int j = i & 7;
    int kc = f >> 2, nt = f & 3;
    int oc = nt * 16 + (l & 15);
    int K  = kc * 32 + ((l >> 4) << 3) + j;
    int tap = K >> 6, c = K & 63;
    wTfrag[i] = f2bf(w_def[(size_t)oc * (C_ * K2_) + c * K2_ + tap]);
}

// ---------------------------------------------------------------------------
// K0c: w_off (18,C,3,3) -> wOfrag, bf16 B-fragment order, N padded 18->32.
// ---------------------------------------------------------------------------
__global__ void k_wprep_off(const float* __restrict__ w_off,
                            unsigned short* __restrict__ wOfrag) {
    int i = blockIdx.x * 256 + threadIdx.x;           // over 36*512 = 18432
    if (i >= 36 * 512) return;
    int f = i >> 9;
    int l = (i >> 3) & 63;
    int j = i & 7;
    int kc = f >> 1, nt = f & 1;
    int oc = nt * 16 + (l & 15);
    int K  = kc * 32 + ((l >> 4) << 3) + j;
    int tap = K >> 6, c = K & 63;
    float v = (oc < OFFC) ? w_off[((size_t)oc * C_ + c) * K2_ + tap] : 0.f;
    wOfrag[i] = f2bf(v);
}

// ---------------------------------------------------------------------------
// K1: fused. Block = 64 px, 256 threads (4 waves).
// xs: x window rows h-2..h+2, cols w0-3..w0+68, bf16,
//     [q=ch/16][entry=(r,col)][16ch]; byte ^= ((col&7)<<4) ^ (q<<5).
//     Bijective: QS = 360*32, 360%8==0, 72%8==0 (proven round 5; r4 bug was
//     the +32 pad making 361%8==1).
// NO tile buffer: lane l samples rows m*16+(l&15), channels (l>>4)*8..+8 and
// 32+(l>>4)*8..+8 -> exactly its 16x16x32 A-fragment; MFMA fed from registers.
// offsBuf stride 22: (px*22)%32 distinct for px 0..15 -> conflict-free reads.
// LDS = 46080 + 5632 = 51712 -> 3 blocks/CU (12 waves/CU).
// ---------------------------------------------------------------------------
constexpr int QS = 5 * 72 * 32;            // 11520 B per q partition (360 entries)
constexpr int XS_BYTES = 4 * QS;           // 46080

__global__ __launch_bounds__(256, 3) void k_fused(const float* __restrict__ x,
                                                  const unsigned short* __restrict__ wOfrag,
                                                  const float* __restrict__ b_off,
                                                  const unsigned short* __restrict__ wTfrag,
                                                  const float* __restrict__ b_def,
                                                  float* __restrict__ out) {
    __shared__ __align__(16) char xs[XS_BYTES];
    __shared__ float offsBuf[64][22];

    int bid = blockIdx.x;                  // grid = 2048; chunked XCD swizzle
    int swz = (bid & 7) * 256 + (bid >> 3);
    int px0 = swz * 64;
    int b  = px0 >> 14;
    int h  = (px0 >> 7) & (H_ - 1);
    int w0 = px0 & (W_ - 1);               // 0 or 64

    int tid  = threadIdx.x;
    int lane = tid & 63;
    int wave = tid >> 6;

    // --- phase 0: stage x window -> xs (bf16, zero-padded OOB) ---
    for (int it = tid; it < 5760; it += 256) {
        int col = it % 72;
        int rem = it / 72;
        int c4  = rem & 15;                // channel group of 4
        int r   = rem >> 4;                // 0..4
        int y    = h - 2 + r;
        int xcol = w0 - 3 + col;
        bf16x4 pk;
        if (((unsigned)y < (unsigned)H_) && ((unsigned)xcol < (unsigned)W_)) {
            const float* g = x + (((size_t)(b * C_ + c4 * 4) * H_ + y) * W_ + xcol);
            pk[0] = (short)f2bf(g[0]);
            pk[1] = (short)f2bf(g[H_ * W_]);
            pk[2] = (short)f2bf(g[2 * H_ * W_]);
            pk[3] = (short)f2bf(g[3 * H_ * W_]);
        } else {
            pk = (bf16x4){0, 0, 0, 0};
        }
        int q0 = c4 >> 2;
        int byte = q0 * QS + ((r * 72 + col) * 32) + (c4 & 3) * 8;
        byte ^= ((col & 7) << 4) ^ (q0 << 5);
        *reinterpret_cast<bf16x4*>(xs + byte) = pk;
    }
    __syncthreads();

    // --- phase 1: offset GEMM (A-frags straight from xs) -> offsBuf ---
    {
        f32x4 acc2[2];
        acc2[0] = (f32x4){0.f, 0.f, 0.f, 0.f};
        acc2[1] = (f32x4){0.f, 0.f, 0.f, 0.f};
        int g   = lane >> 4;
        int pxr = wave * 16 + (lane & 15);
        #pragma unroll
        for (int kc = 0; kc < 18; ++kc) {
            int K   = kc * 32 + g * 8;
            int tap = K >> 6, c = K & 63;
            int ky = tap / 3, kx = tap % 3;
            int col = pxr + kx + 2;
            int r   = ky + 1;
            int qq  = c >> 4;
            int byte = qq * QS + ((r * 72 + col) * 32) + (c & 15) * 2;
            byte ^= ((col & 7) << 4) ^ (qq << 5);
            bf16x8 a  = *reinterpret_cast<const bf16x8*>(xs + byte);
            bf16x8 b0 = *reinterpret_cast<const bf16x8*>(wOfrag + (((kc * 2 + 0) * 64 + lane) << 3));
            bf16x8 b1 = *reinterpret_cast<const bf16x8*>(wOfrag + (((kc * 2 + 1) * 64 + lane) << 3));
            acc2[0] = __builtin_amdgcn_mfma_f32_16x16x32_bf16(a, b0, acc2[0], 0, 0, 0);
            acc2[1] = __builtin_amdgcn_mfma_f32_16x16x32_bf16(a, b1, acc2[1], 0, 0, 0);
        }
        #pragma unroll
        for (int nt = 0; nt < 2; ++nt) {
            int oc = nt * 16 + (lane & 15);
            if (oc < OFFC) {
                float bo = b_off[oc];
                #pragma unroll
                for (int j = 0; j < 4; ++j) {
                    int px = wave * 16 + ((lane >> 4) << 2) + j;
                    offsBuf[px][oc] = acc2[nt][j] + bo;
                }
            }
        }
    }
    __syncthreads();

    // --- phase 2: sample-into-registers + MFMA, barrier-free ---
    f32x4 acc[4];
    #pragma unroll
    for (int m = 0; m < 4; ++m) acc[m] = (f32x4){0.f, 0.f, 0.f, 0.f};

    int g    = lane >> 4;                  // K-group 0..3
    int rowM = lane & 15;                  // M-row within 16-tile
    int glo  = (g & 1) << 4;               // byte offset of 8-ch half in entry
    int qlo  = g >> 1;                     // channels g*8..+8 -> q 0..1
    int qhi  = qlo + 2;                    // channels 32+g*8..+8 -> q 2..3
    int baseLo = qlo * QS, baseHi = qhi * QS;
    int xorLo  = qlo << 5,  xorHi  = qhi << 5;

    for (int ky = 0; ky < 3; ++ky) {
        for (int kx = 0; kx < 3; ++kx) {
            int k = ky * 3 + kx;
            bf16x8 B0 = *reinterpret_cast<const bf16x8*>(
                wTfrag + ((((2 * k + 0) * 4 + wave) * 64 + lane) << 3));
            bf16x8 B1 = *reinterpret_cast<const bf16x8*>(
                wTfrag + ((((2 * k + 1) * 4 + wave) * 64 + lane) << 3));
            #pragma unroll
            for (int m = 0; m < 4; ++m) {
                int px = (m << 4) + rowM;
                float dy = offsBuf[px][2 * k];
                float dx = offsBuf[px][2 * k + 1];
                float py  = (float)(h - 1 + ky) + dy;
                float pxf = (float)(w0 + px - 1 + kx) + dx;
                float y0f = floorf(py), x0f = floorf(pxf);
                float wy = py - y0f, wx = pxf - x0f;
                int y0 = (int)y0f, x0 = (int)x0f;
                int r0 = y0 - (h - 2), c0 = x0 - (w0 - 3);
                float w00 = (1.f - wy) * (1.f - wx);
                float w01 = (1.f - wy) * wx;
                float w10 = wy * (1.f - wx);
                float w11 = wy * wx;

                float slo[8], shi[8];
                if (((unsigned)r0 < 4u) && ((unsigned)c0 < 71u)) {
                    int A00 = ((r0 * 72 + c0) << 5) + glo;
                    int s0 = (c0 & 7) << 4;
                    int s1 = ((c0 + 1) & 7) << 4;
                    bf16x8 p00l = *reinterpret_cast<const bf16x8*>(xs + ((baseLo + A00)        ^ (s0 ^ xorLo)));
                    bf16x8 p01l = *reinterpret_cast<const bf16x8*>(xs + ((baseLo + A00 + 32)   ^ (s1 ^ xorLo)));
                    bf16x8 p10l = *reinterpret_cast<const bf16x8*>(xs + ((baseLo + A00 + 2304) ^ (s0 ^ xorLo)));
                    bf16x8 p11l = *reinterpret_cast<const bf16x8*>(xs + ((baseLo + A00 + 2336) ^ (s1 ^ xorLo)));
                    bf16x8 p00h = *reinterpret_cast<const bf16x8*>(xs + ((baseHi + A00)        ^ (s0 ^ xorHi)));
                    bf16x8 p01h = *reinterpret_cast<const bf16x8*>(xs + ((baseHi + A00 + 32)   ^ (s1 ^ xorHi)));
                    bf16x8 p10h = *reinterpret_cast<const bf16x8*>(xs + ((baseHi + A00 + 2304) ^ (s0 ^ xorHi)));
                    bf16x8 p11h = *reinterpret_cast<const bf16x8*>(xs + ((baseHi + A00 + 2336) ^ (s1 ^ xorHi)));
                    #pragma unroll
                    for (int j = 0; j < 8; ++j) {
                        slo[j] = w00 * bf2f((unsigned short)p00l[j])
                               + w01 * bf2f((unsigned short)p01l[j])
                               + w10 * bf2f((unsigned short)p10l[j])
                               + w11 * bf2f((unsigned short)p11l[j]);
                        shi[j] = w00 * bf2f((unsigned short)p00h[j])
                               + w01 * bf2f((unsigned short)p01h[j])
                               + w10 * bf2f((unsigned short)p10h[j])
                               + w11 * bf2f((unsigned short)p11h[j]);
                    }
                } else {
                    // slow path (rare): reference semantics from global NCHW
                    int y1 = y0 + 1, x1 = x0 + 1;
                    bool vy0 = (y0 >= 0) & (y0 < H_);
                    bool vy1 = (y1 >= 0) & (y1 < H_);
                    bool vx0 = (x0 >= 0) & (x0 < W_);
                    bool vx1 = (x1 >= 0) & (x1 < W_);
                    float m00 = (vy0 && vx0) ? w00 : 0.f;
                    float m01 = (vy0 && vx1) ? w01 : 0.f;
                    float m10 = (vy1 && vx0) ? w10 : 0.f;
                    float m11 = (vy1 && vx1) ? w11 : 0.f;
                    int y0c = min(max(y0, 0), H_ - 1), y1c = min(max(y1, 0), H_ - 1);
                    int x0c = min(max(x0, 0), W_ - 1), x1c = min(max(x1, 0), W_ - 1);
                    int i00 = y0c * W_ + x0c, i01 = y0c * W_ + x1c;
                    int i10 = y1c * W_ + x0c, i11 = y1c * W_ + x1c;
                    const float* cb = x + (size_t)b * C_ * H_ * W_;
                    #pragma unroll
                    for (int j = 0; j < 8; ++j) {
                        const float* cA = cb + (size_t)((g << 3) + j) * (H_ * W_);
                        const float* cB = cb + (size_t)(32 + (g << 3) + j) * (H_ * W_);
                        slo[j] = m00 * tobf_f(cA[i00]) + m01 * tobf_f(cA[i01])
                               + m10 * tobf_f(cA[i10]) + m11 * tobf_f(cA[i11]);
                        shi[j] = m00 * tobf_f(cB[i00]) + m01 * tobf_f(cB[i01])
                               + m10 * tobf_f(cB[i10]) + m11 * tobf_f(cB[i11]);
                    }
                }
                bf16x8 alo, ahi;
                #pragma unroll
                for (int j = 0; j < 8; ++j) {
                    alo[j] = f2bf_s(slo[j]);
                    ahi[j] = f2bf_s(shi[j]);
                }
                acc[m] = __builtin_amdgcn_mfma_f32_16x16x32_bf16(alo, B0, acc[m], 0, 0, 0);
                acc[m] = __builtin_amdgcn_mfma_f32_16x16x32_bf16(ahi, B1, acc[m], 0, 0, 0);
            }
        }
    }
    __syncthreads();

    // --- epilogue: reuse xs as [64][65] f32, coalesced NCHW store ---
    float* ot = reinterpret_cast<float*>(xs);
    float bias = b_def[(wave << 4) + rowM];
    #pragma unroll
    for (int m = 0; m < 4; ++m) {
        #pragma unroll
        for (int j = 0; j < 4; ++j) {
            int prow = (m << 4) + (g << 2) + j;           // pixel
            ot[prow * 65 + (wave << 4) + rowM] = acc[m][j] + bias;
        }
    }
    __syncthreads();
    #pragma unroll
    for (int r = 0; r < 16; ++r) {
        int idx = r * 256 + tid;
        int oc = idx >> 6, pw = idx & 63;
        out[(((size_t)b * O_ + oc) * H_ + h) * W_ + w0 + pw] = ot[pw * 65 + oc];
    }
}

// ---------------------------------------------------------------------------
extern "C" void kernel_launch(void* const* d_in, const int* in_sizes, int n_in,
                              void* d_out, int out_size, void* d_ws, size_t ws_size,
                              hipStream_t stream) {
    const float* x     = (const float*)d_in[0];
    const float* w_off = (const float*)d_in[1];
    const float* b_off = (const float*)d_in[2];
    const float* w_def = (const float*)d_in[3];
    const float* b_def = (const float*)d_in[4];
    float* out = (float*)d_out;

    char* ws = (char*)d_ws;
    unsigned short* wTf = (unsigned short*)ws;            // 73,728 B
    unsigned short* wOf = (unsigned short*)(ws + 73728);  // 36,864 B

    k_wprep<<<(O_ * C_ * K2_ + 255) / 256, 256, 0, stream>>>(w_def, wTf);
    k_wprep_off<<<(36 * 512 + 255) / 256, 256, 0, stream>>>(w_off, wOf);
    k_fused<<<NPIX / 64, 256, 0, stream>>>(x, wOf, b_off, wTf, b_def, out);
}

// Round 7
// 71.026 us; speedup vs baseline: 1.8543x; 1.8127x over previous
//
#include <hip/hip_runtime.h>
#include <hip/hip_bf16.h>

// Problem constants (fixed by setup_inputs)
constexpr int B_ = 8, C_ = 64, O_ = 64, H_ = 128, W_ = 128;
constexpr int K2_ = 9, OFFC = 18;          // 2*K2
constexpr int NPIX = B_ * H_ * W_;         // 131072

typedef __attribute__((ext_vector_type(8))) short bf16x8;
typedef __attribute__((ext_vector_type(4))) short bf16x4;
typedef __attribute__((ext_vector_type(4))) float f32x4;

__device__ __forceinline__ unsigned short f2bf(float f) {
    unsigned int u = __float_as_uint(f);
    u += 0x7fffu + ((u >> 16) & 1u);       // round-to-nearest-even
    return (unsigned short)(u >> 16);
}
__device__ __forceinline__ float bf2f(unsigned short s) {
    return __uint_as_float(((unsigned)s) << 16);
}
__device__ __forceinline__ float tobf_f(float v) {   // round-trip through bf16
    return bf2f(f2bf(v));
}
__device__ __forceinline__ short f2bf_s(float f) {   // single-instr cvt path
    __hip_bfloat16 t = __float2bfloat16(f);
    return *reinterpret_cast<short*>(&t);
}

// ---------------------------------------------------------------------------
// K0b: w_def (O,C,3,3) -> wTfrag, bf16 in MFMA B-fragment order.
// frag f = kc*4 + nt; lane l, elem j: oc = nt*16+(l&15); K = kc*32+(l>>4)*8+j
// K = tap*64 + c
// ---------------------------------------------------------------------------
__global__ void k_wprep(const float* __restrict__ w_def,
                        unsigned short* __restrict__ wTfrag) {
    int i = blockIdx.x * 256 + threadIdx.x;           // over 72*512 = 36864
    if (i >= O_ * C_ * K2_) return;
    int f = i >> 9;            // /512
    int l = (i >> 3) & 63;
    int j = i & 7;
    int kc = f >> 2, nt = f & 3;
    int oc = nt * 16 + (l & 15);
    int K  = kc * 32 + ((l >> 4) << 3) + j;
    int tap = K >> 6, c = K & 63;
    wTfrag[i] = f2bf(w_def[(size_t)oc * (C_ * K2_) + c * K2_ + tap]);
}

// ---------------------------------------------------------------------------
// K0c: w_off (18,C,3,3) -> wOfrag, bf16 B-fragment order, N padded 18->32.
// ---------------------------------------------------------------------------
__global__ void k_wprep_off(const float* __restrict__ w_off,
                            unsigned short* __restrict__ wOfrag) {
    int i = blockIdx.x * 256 + threadIdx.x;           // over 36*512 = 18432
    if (i >= 36 * 512) return;
    int f = i >> 9;
    int l = (i >> 3) & 63;
    int j = i & 7;
    int kc = f >> 1, nt = f & 1;
    int oc = nt * 16 + (l & 15);
    int K  = kc * 32 + ((l >> 4) << 3) + j;
    int tap = K >> 6, c = K & 63;
    float v = (oc < OFFC) ? w_off[((size_t)oc * C_ + c) * K2_ + tap] : 0.f;
    wOfrag[i] = f2bf(v);
}

// ---------------------------------------------------------------------------
// K1: fused. Block = 64 px, 256 threads (4 waves).
// xs: x window rows h-2..h+2, cols w0-3..w0+68, bf16,
//     [q=ch/16][entry=(r,col)][16ch]; byte ^= ((col&7)<<4) ^ (q<<5).
//     Bijective: QS = 360*32, 360%8==0, 72%8==0 (proven round 5).
// Wave decomposition (round-7 fix of the 4x sampling redundancy):
//   wave w owns px subtile [w*16, w*16+16) x ALL 64 oc. Lane l samples ONE
//   px row (w*16 + (l&15)), channels (l>>4)*8..+8 / 32+(l>>4)*8..+8 -> its
//   A-fragment once per tap, reused by 4 oc-tile MFMAs (B from global L2).
// LDS = 46080 + 5632 = 51712 -> 3 blocks/CU (12 waves/CU).
// ---------------------------------------------------------------------------
constexpr int QS = 5 * 72 * 32;            // 11520 B per q partition (360 entries)
constexpr int XS_BYTES = 4 * QS;           // 46080

__global__ __launch_bounds__(256, 3) void k_fused(const float* __restrict__ x,
                                                  const unsigned short* __restrict__ wOfrag,
                                                  const float* __restrict__ b_off,
                                                  const unsigned short* __restrict__ wTfrag,
                                                  const float* __restrict__ b_def,
                                                  float* __restrict__ out) {
    __shared__ __align__(16) char xs[XS_BYTES];
    __shared__ float offsBuf[64][22];

    int bid = blockIdx.x;                  // grid = 2048; chunked XCD swizzle
    int swz = (bid & 7) * 256 + (bid >> 3);
    int px0 = swz * 64;
    int b  = px0 >> 14;
    int h  = (px0 >> 7) & (H_ - 1);
    int w0 = px0 & (W_ - 1);               // 0 or 64

    int tid  = threadIdx.x;
    int lane = tid & 63;
    int wave = tid >> 6;

    // --- phase 0: stage x window -> xs (bf16, zero-padded OOB) ---
    for (int it = tid; it < 5760; it += 256) {
        int col = it % 72;
        int rem = it / 72;
        int c4  = rem & 15;                // channel group of 4
        int r   = rem >> 4;                // 0..4
        int y    = h - 2 + r;
        int xcol = w0 - 3 + col;
        bf16x4 pk;
        if (((unsigned)y < (unsigned)H_) && ((unsigned)xcol < (unsigned)W_)) {
            const float* g = x + (((size_t)(b * C_ + c4 * 4) * H_ + y) * W_ + xcol);
            pk[0] = f2bf_s(g[0]);
            pk[1] = f2bf_s(g[H_ * W_]);
            pk[2] = f2bf_s(g[2 * H_ * W_]);
            pk[3] = f2bf_s(g[3 * H_ * W_]);
        } else {
            pk = (bf16x4){0, 0, 0, 0};
        }
        int q0 = c4 >> 2;
        int byte = q0 * QS + ((r * 72 + col) * 32) + (c4 & 3) * 8;
        byte ^= ((col & 7) << 4) ^ (q0 << 5);
        *reinterpret_cast<bf16x4*>(xs + byte) = pk;
    }
    __syncthreads();

    // --- phase 1: offset GEMM (A-frags straight from xs) -> offsBuf ---
    {
        f32x4 acc2[2];
        acc2[0] = (f32x4){0.f, 0.f, 0.f, 0.f};
        acc2[1] = (f32x4){0.f, 0.f, 0.f, 0.f};
        int g   = lane >> 4;
        int pxr = wave * 16 + (lane & 15);
        #pragma unroll
        for (int kc = 0; kc < 18; ++kc) {
            int K   = kc * 32 + g * 8;
            int tap = K >> 6, c = K & 63;
            int ky = tap / 3, kx = tap % 3;
            int col = pxr + kx + 2;
            int r   = ky + 1;
            int qq  = c >> 4;
            int byte = qq * QS + ((r * 72 + col) * 32) + (c & 15) * 2;
            byte ^= ((col & 7) << 4) ^ (qq << 5);
            bf16x8 a  = *reinterpret_cast<const bf16x8*>(xs + byte);
            bf16x8 b0 = *reinterpret_cast<const bf16x8*>(wOfrag + (((kc * 2 + 0) * 64 + lane) << 3));
            bf16x8 b1 = *reinterpret_cast<const bf16x8*>(wOfrag + (((kc * 2 + 1) * 64 + lane) << 3));
            acc2[0] = __builtin_amdgcn_mfma_f32_16x16x32_bf16(a, b0, acc2[0], 0, 0, 0);
            acc2[1] = __builtin_amdgcn_mfma_f32_16x16x32_bf16(a, b1, acc2[1], 0, 0, 0);
        }
        #pragma unroll
        for (int nt = 0; nt < 2; ++nt) {
            int oc = nt * 16 + (lane & 15);
            if (oc < OFFC) {
                float bo = b_off[oc];
                #pragma unroll
                for (int j = 0; j < 4; ++j) {
                    int px = wave * 16 + ((lane >> 4) << 2) + j;
                    offsBuf[px][oc] = acc2[nt][j] + bo;
                }
            }
        }
    }
    __syncthreads();

    // --- phase 2: sample ONCE per (px,tap), 8 MFMAs reuse the fragment ---
    f32x4 acc[4];                          // indexed by oc tile nt (unrolled)
    #pragma unroll
    for (int nt = 0; nt < 4; ++nt) acc[nt] = (f32x4){0.f, 0.f, 0.f, 0.f};

    int g    = lane >> 4;                  // K-group 0..3
    int rowM = lane & 15;
    int pxw  = (wave << 4) + rowM;         // the block-local px this lane samples
    int glo  = (g & 1) << 4;               // byte offset of 8-ch half in entry
    int qlo  = g >> 1;                     // channels g*8..+8 -> q 0..1
    int qhi  = qlo + 2;                    // channels 32+g*8..+8 -> q 2..3
    int baseLo = qlo * QS, baseHi = qhi * QS;
    int xorLo  = qlo << 5,  xorHi  = qhi << 5;

    #pragma unroll
    for (int ky = 0; ky < 3; ++ky) {
        #pragma unroll
        for (int kx = 0; kx < 3; ++kx) {
            int k = ky * 3 + kx;
            // B fragments for all 4 oc tiles, both K halves. Issued at loop
            // top; consumed only at the MFMAs -> sampling hides L2 latency.
            bf16x8 B0[4], B1[4];
            #pragma unroll
            for (int nt = 0; nt < 4; ++nt) {
                B0[nt] = *reinterpret_cast<const bf16x8*>(
                    wTfrag + ((((2 * k + 0) * 4 + nt) * 64 + lane) << 3));
                B1[nt] = *reinterpret_cast<const bf16x8*>(
                    wTfrag + ((((2 * k + 1) * 4 + nt) * 64 + lane) << 3));
            }

            float2 dv = *reinterpret_cast<const float2*>(&offsBuf[pxw][2 * k]);
            float py  = (float)(h - 1 + ky) + dv.x;
            float pxf = (float)(w0 + pxw - 1 + kx) + dv.y;
            float y0f = floorf(py), x0f = floorf(pxf);
            float wy = py - y0f, wx = pxf - x0f;
            int y0 = (int)y0f, x0 = (int)x0f;
            int r0 = y0 - (h - 2), c0 = x0 - (w0 - 3);
            float w00 = (1.f - wy) * (1.f - wx);
            float w01 = (1.f - wy) * wx;
            float w10 = wy * (1.f - wx);
            float w11 = wy * wx;

            float slo[8], shi[8];
            if (((unsigned)r0 < 4u) && ((unsigned)c0 < 71u)) {
                int A00 = ((r0 * 72 + c0) << 5) + glo;
                int s0 = (c0 & 7) << 4;
                int s1 = ((c0 + 1) & 7) << 4;
                bf16x8 p00l = *reinterpret_cast<const bf16x8*>(xs + ((baseLo + A00)        ^ (s0 ^ xorLo)));
                bf16x8 p01l = *reinterpret_cast<const bf16x8*>(xs + ((baseLo + A00 + 32)   ^ (s1 ^ xorLo)));
                bf16x8 p10l = *reinterpret_cast<const bf16x8*>(xs + ((baseLo + A00 + 2304) ^ (s0 ^ xorLo)));
                bf16x8 p11l = *reinterpret_cast<const bf16x8*>(xs + ((baseLo + A00 + 2336) ^ (s1 ^ xorLo)));
                bf16x8 p00h = *reinterpret_cast<const bf16x8*>(xs + ((baseHi + A00)        ^ (s0 ^ xorHi)));
                bf16x8 p01h = *reinterpret_cast<const bf16x8*>(xs + ((baseHi + A00 + 32)   ^ (s1 ^ xorHi)));
                bf16x8 p10h = *reinterpret_cast<const bf16x8*>(xs + ((baseHi + A00 + 2304) ^ (s0 ^ xorHi)));
                bf16x8 p11h = *reinterpret_cast<const bf16x8*>(xs + ((baseHi + A00 + 2336) ^ (s1 ^ xorHi)));
                #pragma unroll
                for (int j = 0; j < 8; ++j) {
                    slo[j] = w00 * bf2f((unsigned short)p00l[j])
                           + w01 * bf2f((unsigned short)p01l[j])
                           + w10 * bf2f((unsigned short)p10l[j])
                           + w11 * bf2f((unsigned short)p11l[j]);
                    shi[j] = w00 * bf2f((unsigned short)p00h[j])
                           + w01 * bf2f((unsigned short)p01h[j])
                           + w10 * bf2f((unsigned short)p10h[j])
                           + w11 * bf2f((unsigned short)p11h[j]);
                }
            } else {
                // slow path (rare): reference semantics from global NCHW
                int y1 = y0 + 1, x1 = x0 + 1;
                bool vy0 = (y0 >= 0) & (y0 < H_);
                bool vy1 = (y1 >= 0) & (y1 < H_);
                bool vx0 = (x0 >= 0) & (x0 < W_);
                bool vx1 = (x1 >= 0) & (x1 < W_);
                float m00 = (vy0 && vx0) ? w00 : 0.f;
                float m01 = (vy0 && vx1) ? w01 : 0.f;
                float m10 = (vy1 && vx0) ? w10 : 0.f;
                float m11 = (vy1 && vx1) ? w11 : 0.f;
                int y0c = min(max(y0, 0), H_ - 1), y1c = min(max(y1, 0), H_ - 1);
                int x0c = min(max(x0, 0), W_ - 1), x1c = min(max(x1, 0), W_ - 1);
                int i00 = y0c * W_ + x0c, i01 = y0c * W_ + x1c;
                int i10 = y1c * W_ + x0c, i11 = y1c * W_ + x1c;
                const float* cb = x + (size_t)b * C_ * H_ * W_;
                #pragma unroll
                for (int j = 0; j < 8; ++j) {
                    const float* cA = cb + (size_t)((g << 3) + j) * (H_ * W_);
                    const float* cB = cb + (size_t)(32 + (g << 3) + j) * (H_ * W_);
                    slo[j] = m00 * tobf_f(cA[i00]) + m01 * tobf_f(cA[i01])
                           + m10 * tobf_f(cA[i10]) + m11 * tobf_f(cA[i11]);
                    shi[j] = m00 * tobf_f(cB[i00]) + m01 * tobf_f(cB[i01])
                           + m10 * tobf_f(cB[i10]) + m11 * tobf_f(cB[i11]);
                }
            }
            bf16x8 alo, ahi;
            #pragma unroll
            for (int j = 0; j < 8; ++j) {
                alo[j] = f2bf_s(slo[j]);
                ahi[j] = f2bf_s(shi[j]);
            }
            #pragma unroll
            for (int nt = 0; nt < 4; ++nt)
                acc[nt] = __builtin_amdgcn_mfma_f32_16x16x32_bf16(alo, B0[nt], acc[nt], 0, 0, 0);
            #pragma unroll
            for (int nt = 0; nt < 4; ++nt)
                acc[nt] = __builtin_amdgcn_mfma_f32_16x16x32_bf16(ahi, B1[nt], acc[nt], 0, 0, 0);
        }
    }
    __syncthreads();

    // --- epilogue: reuse xs as [64][65] f32, coalesced NCHW store ---
    // C layout: oc = nt*16 + (lane&15); px = wave*16 + (lane>>4)*4 + j
    float* ot = reinterpret_cast<float*>(xs);
    #pragma unroll
    for (int nt = 0; nt < 4; ++nt) {
        int oc = (nt << 4) + rowM;
        #pragma unroll
        for (int j = 0; j < 4; ++j) {
            int prow = (wave << 4) + (g << 2) + j;        // block-local pixel
            ot[prow * 65 + oc] = acc[nt][j];
        }
    }
    __syncthreads();
    #pragma unroll
    for (int r = 0; r < 16; ++r) {
        int idx = r * 256 + tid;
        int oc = idx >> 6, pw = idx & 63;
        out[(((size_t)b * O_ + oc) * H_ + h) * W_ + w0 + pw] = ot[pw * 65 + oc] + b_def[oc];
    }
}

// ---------------------------------------------------------------------------
extern "C" void kernel_launch(void* const* d_in, const int* in_sizes, int n_in,
                              void* d_out, int out_size, void* d_ws, size_t ws_size,
                              hipStream_t stream) {
    const float* x     = (const float*)d_in[0];
    const float* w_off = (const float*)d_in[1];
    const float* b_off = (const float*)d_in[2];
    const float* w_def = (const float*)d_in[3];
    const float* b_def = (const float*)d_in[4];
    float* out = (float*)d_out;

    char* ws = (char*)d_ws;
    unsigned short* wTf = (unsigned short*)ws;            // 73,728 B
    unsigned short* wOf = (unsigned short*)(ws + 73728);  // 36,864 B

    k_wprep<<<(O_ * C_ * K2_ + 255) / 256, 256, 0, stream>>>(w_def, wTf);
    k_wprep_off<<<(36 * 512 + 255) / 256, 256, 0, stream>>>(w_off, wOf);
    k_fused<<<NPIX / 64, 256, 0, stream>>>(x, wOf, b_off, wTf, b_def, out);
}